// Round 14
// baseline (218.891 us; speedup 1.0000x reference)
//
#include <hip/hip_runtime.h>
#include <math.h>

// Problem constants (B=4, S=4096, H=4096, E=64, top_k=8)
#define TOKENS 16384   // B*S
#define HDIM   4096
#define NEXP   64
#define TOPK   8

#define TAU 1.5e-4f    // certify margin; logit err RMS ~2e-6 -> TAU/2 = 37 sigma

#define BM  32
#define BK  64
#define KSP 2                    // split-K factor
#define KHALF (HDIM / KSP)       // 2048
#define NCH (KHALF / BK)         // 32 chunks per block
#define CLC(C) ((C) < NCH ? (C) : NCH - 1)

typedef short bf16x8 __attribute__((ext_vector_type(8)));
typedef float f32x4  __attribute__((ext_vector_type(4)));

__device__ __forceinline__ unsigned bf16_rne(float f) {
    unsigned u = __float_as_uint(f);
    return (u + 0x7fffu + ((u >> 16) & 1u)) >> 16;
}
__device__ __forceinline__ float bf16_tof(unsigned h) { return __uint_as_float(h << 16); }

// ================= B pre-split: wgt fp32 -> 3 bf16 planes in d_ws ==============
__global__ __launch_bounds__(256) void bsplit_kernel(const float* __restrict__ wgt,
                                                     short* __restrict__ bsp,
                                                     int* __restrict__ cnt) {
    if (blockIdx.x == 0 && threadIdx.x == 0) *cnt = 0;
    const int base = 4 * (blockIdx.x * 256 + threadIdx.x);
    float4 w = *reinterpret_cast<const float4*>(wgt + base);
    float f[4] = {w.x, w.y, w.z, w.w};
    short h0[4], h1[4], h2[4];
#pragma unroll
    for (int e = 0; e < 4; ++e) {
        unsigned b0 = bf16_rne(f[e]); float r1 = f[e] - bf16_tof(b0);
        unsigned b1 = bf16_rne(r1);   float r2 = r1 - bf16_tof(b1);
        unsigned b2 = bf16_rne(r2);
        h0[e] = (short)b0; h1[e] = (short)b1; h2[e] = (short)b2;
    }
    *reinterpret_cast<short4*>(bsp + 0 * 262144 + base) = make_short4(h0[0], h0[1], h0[2], h0[3]);
    *reinterpret_cast<short4*>(bsp + 1 * 262144 + base) = make_short4(h1[0], h1[1], h1[2], h1[3]);
    *reinterpret_cast<short4*>(bsp + 2 * 262144 + base) = make_short4(h2[0], h2[1], h2[2], h2[3]);
}

// ====== GEMM: r13 skeleton + split-K (grid 512x2 -> 4 blocks/CU) ==============
// Block (bx, kh) = 32 tokens x 64 cols x k-half kh. Per chunk (BK=64): A fp32
// global->regs (2-deep named prefetch, A issued before B: oldest-in-FIFO =
// longest latency) -> split to bf16x3 at staging -> swizzled LDS (dbuf);
// B bf16x8 frags from L2-resident planes. One __syncthreads per chunk.
// kh=0 writes logits, kh=1 writes partials; combine_kernel adds them.
// 4 independent barrier groups per CU cover each group's drain stalls.
__global__ __launch_bounds__(256) void gemm_bf16x3(const float* __restrict__ hid,
                                                   const short* __restrict__ bsp,
                                                   float* __restrict__ logits,
                                                   float* __restrict__ part) {
    __shared__ __align__(16) short Abf[2][3][2][32][40];  // 30.7 KB

    const int tid  = threadIdx.x;
    const int wv   = tid >> 6, lane = tid & 63;
    const int r    = lane & 15;       // fragment free index
    const int q    = lane >> 4;       // k-slot group (8 k each)
    const int bm   = blockIdx.x * BM;
    const int kh   = blockIdx.y;      // k-half
    const size_t k0 = (size_t)kh * KHALF;

    // ---- C/D layout self-calibration (probe MFMAs; proven rounds 10-13) ----
    const short hr  = (short)bf16_rne((float)r);
    const short one = (short)0x3F80;
    bf16x8 pav = {hr, hr, hr, hr, hr, hr, hr, hr};
    bf16x8 pbv = {one, one, one, one, one, one, one, one};
    f32x4 z = {0.f, 0.f, 0.f, 0.f};
    f32x4 rowp = __builtin_amdgcn_mfma_f32_16x16x32_bf16(pav, pbv, z, 0, 0, 0);
    f32x4 colp = __builtin_amdgcn_mfma_f32_16x16x32_bf16(pbv, pav, z, 0, 0, 0);
    int drow[4], dcol[4];
#pragma unroll
    for (int j = 0; j < 4; ++j) {
        drow[j] = (int)(rowp[j] * (1.f / 32.f) + 0.5f);
        dcol[j] = (int)(colp[j] * (1.f / 32.f) + 0.5f);
    }

    f32x4 acc[2] = {z, z};            // [row-tile 0/1], 16 cols each

    // staging: thread t -> row t>>3, 8-float k-group t&7 of the 32x64 A chunk
    const int srow = tid >> 3;
    const int sk8  = tid & 7;
    const int sks  = sk8 >> 2;                 // ksub 0/1
    const int swu  = (sk8 & 3) ^ (srow & 3);   // XOR-swizzled 16B unit
    const float* asrc = hid + (size_t)(bm + srow) * HDIM + k0 + 8 * sk8;

    // B per-lane plane pointers (col = 16wv + r)
    const short* bp0 = bsp + ((size_t)0 * NEXP + 16 * wv + r) * HDIM + k0 + 8 * q;
    const short* bp1 = bp0 + (size_t)NEXP * HDIM;
    const short* bp2 = bp1 + (size_t)NEXP * HDIM;

    float4 paX[2], paY[2];            // A raw prefetch (named sets, depth 2)
    bf16x8 BX[2][3], BY[2][3];        // B fragment sets [ksub][plane], depth 2

#define LOADA(P, C) do { \
        P[0] = *reinterpret_cast<const float4*>(asrc + CLC(C) * 64); \
        P[1] = *reinterpret_cast<const float4*>(asrc + CLC(C) * 64 + 4); \
    } while (0)

#define LOADB(S, C) do { \
        _Pragma("unroll") \
        for (int ks_ = 0; ks_ < 2; ++ks_) { \
            S[ks_][0] = *reinterpret_cast<const bf16x8*>(bp0 + CLC(C) * 64 + 32 * ks_); \
            S[ks_][1] = *reinterpret_cast<const bf16x8*>(bp1 + CLC(C) * 64 + 32 * ks_); \
            S[ks_][2] = *reinterpret_cast<const bf16x8*>(bp2 + CLC(C) * 64 + 32 * ks_); \
        } \
    } while (0)

    // split 8 fp32 -> 3 bf16 planes, one b128 LDS write per plane (swizzled unit)
#define SPLITW(P, BUF) do { \
        float f_[8] = {P[0].x, P[0].y, P[0].z, P[0].w, P[1].x, P[1].y, P[1].z, P[1].w}; \
        bf16x8 v0_, v1_, v2_; \
        _Pragma("unroll") \
        for (int i_ = 0; i_ < 8; ++i_) { \
            unsigned b0_ = __float_as_uint(f_[i_]) & 0xFFFF0000u; \
            float r1_ = f_[i_] - __uint_as_float(b0_); \
            unsigned b1_ = __float_as_uint(r1_) & 0xFFFF0000u; \
            float r2_ = r1_ - __uint_as_float(b1_); \
            unsigned b2_ = __float_as_uint(r2_) & 0xFFFF0000u; \
            v0_[i_] = (short)(b0_ >> 16); v1_[i_] = (short)(b1_ >> 16); v2_[i_] = (short)(b2_ >> 16); } \
        *reinterpret_cast<bf16x8*>(&Abf[BUF][0][sks][srow][8 * swu]) = v0_; \
        *reinterpret_cast<bf16x8*>(&Abf[BUF][1][sks][srow][8 * swu]) = v1_; \
        *reinterpret_cast<bf16x8*>(&Abf[BUF][2][sks][srow][8 * swu]) = v2_; \
    } while (0)

#define COMPUTE(BUF, BS) do { \
        _Pragma("unroll") \
        for (int ks_ = 0; ks_ < 2; ++ks_) \
        { _Pragma("unroll") \
          for (int rt_ = 0; rt_ < 2; ++rt_) { \
            const int ro_ = rt_ * 16 + r, ku_ = 8 * (q ^ (r & 3)); \
            bf16x8 a0_ = *reinterpret_cast<const bf16x8*>(&Abf[BUF][0][ks_][ro_][ku_]); \
            bf16x8 a1_ = *reinterpret_cast<const bf16x8*>(&Abf[BUF][1][ks_][ro_][ku_]); \
            bf16x8 a2_ = *reinterpret_cast<const bf16x8*>(&Abf[BUF][2][ks_][ro_][ku_]); \
            acc[rt_] = __builtin_amdgcn_mfma_f32_16x16x32_bf16(a0_, BS[ks_][0], acc[rt_], 0, 0, 0); \
            acc[rt_] = __builtin_amdgcn_mfma_f32_16x16x32_bf16(a0_, BS[ks_][1], acc[rt_], 0, 0, 0); \
            acc[rt_] = __builtin_amdgcn_mfma_f32_16x16x32_bf16(a1_, BS[ks_][0], acc[rt_], 0, 0, 0); \
            acc[rt_] = __builtin_amdgcn_mfma_f32_16x16x32_bf16(a1_, BS[ks_][1], acc[rt_], 0, 0, 0); \
            acc[rt_] = __builtin_amdgcn_mfma_f32_16x16x32_bf16(a0_, BS[ks_][2], acc[rt_], 0, 0, 0); \
            acc[rt_] = __builtin_amdgcn_mfma_f32_16x16x32_bf16(a2_, BS[ks_][0], acc[rt_], 0, 0, 0); \
          } } \
    } while (0)

    // ---- prologue: chunk 0 staged; A(1) in paX; B(0) in BX ----
    LOADA(paX, 0);
    SPLITW(paX, 0);
    LOADA(paX, 1);
    LOADB(BX, 0);

    // invariant at even-body top: LDS[0]=chunk c, paX=A(c+1), BX=B(c)
    for (int c = 0; c < NCH; c += 2) {
        __syncthreads();                 // LDS[0] ready
        LOADA(paY, c + 2);               // A(c+2): HBM, issue first (oldest in FIFO)
        LOADB(BY, c + 1);                // B(c+1): L2
        COMPUTE(0, BX);                  // chunk c
        SPLITW(paX, 1);                  // A(c+1) -> LDS[1]

        __syncthreads();                 // LDS[1] ready
        LOADA(paX, c + 3);               // A(c+3)
        LOADB(BX, c + 2);                // B(c+2)
        COMPUTE(1, BY);                  // chunk c+1
        SPLITW(paY, 0);                  // A(c+2) -> LDS[0]
    }

#undef LOADA
#undef LOADB
#undef SPLITW
#undef COMPUTE

    // ---- epilogue: probe-derived scatter to logits (kh=0) or partials (kh=1) ----
    float* out = (kh == 0) ? logits : part;
#pragma unroll
    for (int rt = 0; rt < 2; ++rt)
#pragma unroll
        for (int j = 0; j < 4; ++j)
            out[(size_t)(bm + rt * 16 + drow[j]) * NEXP + 16 * wv + dcol[j]] = acc[rt][j];
}

// ================= combine: logits += partials (split-K reduction) =============
__global__ __launch_bounds__(256) void combine_kernel(float* __restrict__ logits,
                                                      const float* __restrict__ part) {
    const size_t i = 4 * ((size_t)blockIdx.x * 256 + threadIdx.x);
    float4 a = *reinterpret_cast<const float4*>(logits + i);
    float4 b = *reinterpret_cast<const float4*>(part + i);
    a.x += b.x; a.y += b.y; a.z += b.z; a.w += b.w;
    *reinterpret_cast<float4*>(logits + i) = a;
}

// ======== top-k + softmax + margin certification (one wave per token) =========
__global__ __launch_bounds__(256) void topk_margin(const float* __restrict__ logits,
                                                   float* __restrict__ out_idx,
                                                   float* __restrict__ out_w,
                                                   int* __restrict__ cnt,
                                                   int* __restrict__ list) {
    const int wave  = threadIdx.x >> 6;
    const int lane  = threadIdx.x & 63;
    const int token = blockIdx.x * 4 + wave;
    if (token >= TOKENS) return;

    float v = logits[(size_t)token * NEXP + lane];

    float myval = 0.f; int myidx = 0; float max0 = 0.f;

#pragma unroll
    for (int k = 0; k < TOPK + 1; ++k) {       // top-9: rank-9 needed for margin
        float bv = v; int bi = lane;
#pragma unroll
        for (int off = 32; off > 0; off >>= 1) {   // argmax, tie -> lower index
            float ov = __shfl_xor(bv, off);
            int   oi = __shfl_xor(bi, off);
            if (ov > bv || (ov == bv && oi < bi)) { bv = ov; bi = oi; }
        }
        if (k == 0) max0 = bv;
        if (lane == k) { myval = bv; myidx = bi; }
        if (lane == bi) v = -INFINITY;
    }

    const float nxt = __shfl(myval, lane + 1);
    const bool  bad = (lane < TOPK) && (myval - nxt < TAU);
    const bool  flagged = __any(bad);

    float e = (lane < TOPK) ? expf(myval - max0) : 0.f;
    float s = e;
#pragma unroll
    for (int off = 4; off > 0; off >>= 1) s += __shfl_xor(s, off);

    if (lane < TOPK) {
        size_t o = (size_t)token * TOPK + lane;
        out_idx[o] = (float)myidx;
        out_w[o]   = e / s;
    }
    if (flagged && lane == 0) {
        int slot = atomicAdd(cnt, 1);
        if (slot < TOKENS) list[slot] = token;
    }
}

// ======== exact fp64 recheck of flagged tokens (ordering ground truth) ========
__global__ __launch_bounds__(256) void recheck_kernel(const float* __restrict__ hid,
                                                      const float* __restrict__ wgt,
                                                      const int* __restrict__ cnt,
                                                      const int* __restrict__ list,
                                                      float* __restrict__ out_idx,
                                                      float* __restrict__ out_w) {
    __shared__ double dlog[NEXP];
    const int tid  = threadIdx.x;
    const int wv   = tid >> 6, lane = tid & 63;
    const int eg   = lane >> 4;
    const int kl   = lane & 15;
    const int n    = *cnt;

    for (int it = blockIdx.x; it < n && it < TOKENS; it += gridDim.x) {
        const int token = list[it];
        const float* hrow = hid + (size_t)token * HDIM;
#pragma unroll 1
        for (int pass = 0; pass < 4; ++pass) {
            const int e = wv * 16 + pass * 4 + eg;
            const float* wrow = wgt + (size_t)e * HDIM;
            double p = 0.0;
            for (int k0 = kl * 4; k0 < HDIM; k0 += 64) {
                float4 hv = *reinterpret_cast<const float4*>(hrow + k0);
                float4 wl = *reinterpret_cast<const float4*>(wrow + k0);
                p = fma((double)hv.x, (double)wl.x, p);
                p = fma((double)hv.y, (double)wl.y, p);
                p = fma((double)hv.z, (double)wl.z, p);
                p = fma((double)hv.w, (double)wl.w, p);
            }
#pragma unroll
            for (int off = 8; off > 0; off >>= 1) p += __shfl_xor(p, off);
            if (kl == 0) dlog[e] = p;
        }
        __syncthreads();
        if (wv == 0) {
            double v = dlog[lane];
            double myval = 0.0; int myidx = 0; double m0 = 0.0;
#pragma unroll
            for (int k = 0; k < TOPK; ++k) {
                double bv = v; int bi = lane;
#pragma unroll
                for (int off = 32; off > 0; off >>= 1) {
                    double ov = __shfl_xor(bv, off);
                    int    oi = __shfl_xor(bi, off);
                    if (ov > bv || (ov == bv && oi < bi)) { bv = ov; bi = oi; }
                }
                if (k == 0) m0 = bv;
                if (lane == k) { myval = bv; myidx = bi; }
                if (lane == bi) v = -INFINITY;
            }
            double ee = (lane < TOPK) ? exp(myval - m0) : 0.0;
            double ss = ee;
#pragma unroll
            for (int off = 4; off > 0; off >>= 1) ss += __shfl_xor(ss, off);
            if (lane < TOPK) {
                size_t o = (size_t)token * TOPK + lane;
                out_idx[o] = (float)myidx;
                out_w[o]   = (float)(ee / ss);
            }
        }
        __syncthreads();
    }
}

extern "C" void kernel_launch(void* const* d_in, const int* in_sizes, int n_in,
                              void* d_out, int out_size, void* d_ws, size_t ws_size,
                              hipStream_t stream) {
    const float* hid = (const float*)d_in[0];
    const float* wgt = (const float*)d_in[1];

    float* logits  = (float*)d_out;
    float* out_idx = logits + (size_t)TOKENS * NEXP;
    float* out_w   = out_idx + (size_t)TOKENS * TOPK;

    short* bsp  = (short*)d_ws;                                  // 1.5 MB bf16 planes
    int*   cnt  = (int*)((char*)d_ws + 3 * NEXP * HDIM * 2);
    int*   list = cnt + 1;
    float* part = (float*)(list + TOKENS);                       // 4 MB split-K partials

    bsplit_kernel <<<256, 256, 0, stream>>>(wgt, bsp, cnt);
    gemm_bf16x3   <<<dim3(TOKENS / BM, KSP), 256, 0, stream>>>(hid, bsp, logits, part);
    combine_kernel<<<(TOKENS * NEXP) / 1024, 256, 0, stream>>>(logits, part);
    topk_margin   <<<TOKENS / 4, 256, 0, stream>>>(logits, out_idx, out_w, cnt, list);
    recheck_kernel<<<256, 256, 0, stream>>>(hid, wgt, cnt, list, out_idx, out_w);
}